// Round 5
// baseline (375.166 us; speedup 1.0000x reference)
//
#include <hip/hip_runtime.h>
#include <math.h>

// Problem constants
#define NPIX   131072      // 32 * 64 * 64 pixels
#define KCODES 512
#define DDIM   64
#define HWSZ   4096        // 64*64
#define NELEM  8388608     // NPIX * DDIM

// d_out layout (fp32): [0]=loss, [1..1+NELEM)=q_nchw, [1+NELEM]=perplexity,
// [2+NELEM .. 2+2*NELEM)=q_nhwc flat
#define OUT_NCHW_OFF 1
#define OUT_PERP_IDX (1 + NELEM)
#define OUT_NHWC_OFF (2 + NELEM)

// ws layout (fp32 words): [0]=loss, [16..528)=|e|^2, [544..1056)=counts(uint),
// [1056]=done counter, [2048..)=e bf16 hi/lo B-fragments (128KB)
#define WS_NRM_OFF  16
#define WS_CNT_OFF  544
#define WS_FRAG_F32 2048

typedef __bf16 bf16x8 __attribute__((ext_vector_type(8)));
typedef float  f32x4  __attribute__((ext_vector_type(4)));

// One prep kernel: B-fragment pack + |e|^2 (bit-identical fmaf chain to the
// passing R1/R3/R4 runs) + zero the loss/count/done words (ws is re-poisoned
// 0xAA before every call). Runs before vq_main in stream order.
__global__ __launch_bounds__(256) void vq_prep(const float* __restrict__ emb,
                                               float* __restrict__ ws) {
    int tid  = blockIdx.x * 256 + threadIdx.x;   // 0..8191
    int lane = tid & 63;
    int h    = (tid >> 6) & 1;
    int ks   = (tid >> 7) & 1;
    int ct   = tid >> 8;                         // == blockIdx.x (0..31)
    int code = ct * 16 + (lane & 15);
    int d0   = ks * 32 + ((lane >> 4) & 3) * 8;
    const float* src = emb + code * DDIM + d0;
    unsigned short us[8];
#pragma unroll
    for (int j = 0; j < 8; ++j) {
        float f = src[j];
        __bf16 hb = (__bf16)f;                   // RTN
        if (h == 0) {
            us[j] = __builtin_bit_cast(unsigned short, hb);
        } else {
            __bf16 lb = (__bf16)(f - (float)hb);
            us[j] = __builtin_bit_cast(unsigned short, lb);
        }
    }
    uint4 v;
    v.x = us[0] | ((unsigned)us[1] << 16);
    v.y = us[2] | ((unsigned)us[3] << 16);
    v.z = us[4] | ((unsigned)us[5] << 16);
    v.w = us[6] | ((unsigned)us[7] << 16);
    reinterpret_cast<uint4*>(ws + WS_FRAG_F32)[tid] = v;

    // norms: thread t<16 of block b -> code 16b+t, exact R1 fmaf chain
    if (threadIdx.x < 16) {
        int c = ct * 16 + threadIdx.x;
        const float4* e4 = reinterpret_cast<const float4*>(emb + c * DDIM);
        float s = 0.f;
#pragma unroll
        for (int i = 0; i < 16; ++i) {
            float4 w = e4[i];
            s = fmaf(w.x, w.x, s); s = fmaf(w.y, w.y, s);
            s = fmaf(w.z, w.z, s); s = fmaf(w.w, w.w, s);
        }
        ws[WS_NRM_OFF + c] = s;
    }
    // block 0 zeroes loss + counts + done
    if (blockIdx.x == 0) {
        unsigned* g = reinterpret_cast<unsigned*>(ws);
        g[WS_CNT_OFF + threadIdx.x] = 0u;
        g[WS_CNT_OFF + threadIdx.x + 256] = 0u;
        if (threadIdx.x == 0) { ws[0] = 0.f; g[WS_CNT_OFF + 512] = 0u; }
    }
}

// 512 threads = 8 waves per block of 256 pixels. Waves 0-3: codes 0-255,
// waves 4-7: codes 256-511 -> 4096 waves total (16/CU, 4/SIMD) for latency
// hiding; halves combine argmin via LDS (strict-less = exact first-min since
// half-1 code indices are all larger). A-frags built straight from global
// (no 64KB LDS transpose -> LDS ~23KB, 2 blocks/CU).
__global__ __launch_bounds__(512, 4) void vq_main(const float* __restrict__ in,
                                                  const float* __restrict__ emb,
                                                  float* __restrict__ out,
                                                  float* __restrict__ ws) {
    __shared__ float    q_lds[64 * 65];
    __shared__ float    nrm_lds[KCODES];
    __shared__ float    cbest[256];
    __shared__ int      cidx[256];
    __shared__ float    x2_lds[256];
    __shared__ int      idx_lds[256];
    __shared__ unsigned cnt_lds[KCODES];
    __shared__ float    red_tot;
    __shared__ unsigned last_flag;

    const int t = threadIdx.x;
    const int l = t & 63, w = t >> 6;
    const int half = w >> 2, wp = w & 3;        // code half, pixel group

    cnt_lds[t] = 0u;                             // 512 threads cover 512 counts
    nrm_lds[t] = ws[WS_NRM_OFF + t];
    if (t == 0) { red_tot = 0.f; last_flag = 0u; }

    const int pix0 = blockIdx.x << 8;
    const int b    = pix0 >> 12;
    const int hwb  = pix0 & (HWSZ - 1);
    const float* inb = in + (size_t)b * (DDIM * HWSZ) + hwb;

    // A-fragments (A[m][k]: m=lane&15, k=(lane>>4)*8+j) loaded directly from
    // global: per j-step the wave reads 4 d-rows x 16 consecutive pixels.
    const int q = l >> 4;                        // 0..3
    bf16x8 a_hi[4][2], a_lo[4][2];
    float x2p[4];
#pragma unroll
    for (int pt = 0; pt < 4; ++pt) {
        const float* px = inb + wp * 64 + pt * 16 + (l & 15);
        float x2 = 0.f;
#pragma unroll
        for (int ks = 0; ks < 2; ++ks) {
            const int d0 = ks * 32 + q * 8;
            float fv[8];
#pragma unroll
            for (int j = 0; j < 8; ++j) fv[j] = px[(size_t)(d0 + j) * HWSZ];
            bf16x8 h8, l8;
#pragma unroll
            for (int j = 0; j < 8; ++j) {
                __bf16 hb = (__bf16)fv[j];
                h8[j] = hb;
                l8[j] = (__bf16)(fv[j] - (float)hb);
                x2 = fmaf(fv[j], fv[j], x2);
            }
            a_hi[pt][ks] = h8; a_lo[pt][ks] = l8;
        }
        x2p[pt] = x2;
    }
    // full |x|^2 per pixel column (reduce over lane quarters)
#pragma unroll
    for (int pt = 0; pt < 4; ++pt) {
        x2p[pt] += __shfl_xor(x2p[pt], 16, 64);
        x2p[pt] += __shfl_xor(x2p[pt], 32, 64);
    }
    if (half == 0 && (l & 15) == l) {            // lanes 0..15 of half-0 waves
#pragma unroll
        for (int pt = 0; pt < 4; ++pt) x2_lds[wp * 64 + pt * 16 + l] = x2p[pt];
    }

    const uint4* fragp = reinterpret_cast<const uint4*>(ws + WS_FRAG_F32);
    float best[4][4]; int bidx[4][4];
#pragma unroll
    for (int pt = 0; pt < 4; ++pt)
#pragma unroll
    for (int r = 0; r < 4; ++r) { best[pt][r] = 3.4e38f; bidx[pt][r] = 0; }

    const int ctb0 = half * 16;                  // this half's first 16-code tile
    uint4 bcur[8], bnxt[8];
#pragma unroll
    for (int i = 0; i < 8; ++i) {
        int ct = i >> 2, ks = (i >> 1) & 1, h = i & 1;
        bcur[i] = fragp[(((ctb0 + ct) * 2 + ks) * 2 + h) * 64 + l];
    }
    __syncthreads();   // nrm_lds / cnt_lds / x2_lds ready

    for (int cb = 0; cb < 256; cb += 32) {
        const int ctb = ctb0 + (cb >> 4);
        if (cb + 32 < 256) {
#pragma unroll
            for (int i = 0; i < 8; ++i) {
                int ct = i >> 2, ks = (i >> 1) & 1, h = i & 1;
                bnxt[i] = fragp[(((ctb + 2 + ct) * 2 + ks) * 2 + h) * 64 + l];
            }
        }
        f32x4 acc[4][2];
#pragma unroll
        for (int pt = 0; pt < 4; ++pt)
#pragma unroll
        for (int ct = 0; ct < 2; ++ct) {
            f32x4 a = {0.f, 0.f, 0.f, 0.f};
#pragma unroll
            for (int ks = 0; ks < 2; ++ks) {
                bf16x8 bh = __builtin_bit_cast(bf16x8, bcur[ct * 4 + ks * 2 + 0]);
                bf16x8 bl = __builtin_bit_cast(bf16x8, bcur[ct * 4 + ks * 2 + 1]);
                a = __builtin_amdgcn_mfma_f32_16x16x32_bf16(a_hi[pt][ks], bh, a, 0, 0, 0);
                a = __builtin_amdgcn_mfma_f32_16x16x32_bf16(a_hi[pt][ks], bl, a, 0, 0, 0);
                a = __builtin_amdgcn_mfma_f32_16x16x32_bf16(a_lo[pt][ks], bh, a, 0, 0, 0);
                a = __builtin_amdgcn_mfma_f32_16x16x32_bf16(a_lo[pt][ks], bl, a, 0, 0, 0);
            }
            acc[pt][ct] = a;
        }
#pragma unroll
        for (int ct = 0; ct < 2; ++ct) {
            int code = half * 256 + cb + ct * 16 + (l & 15);
            float nv = nrm_lds[code];
#pragma unroll
            for (int pt = 0; pt < 4; ++pt)
#pragma unroll
            for (int r = 0; r < 4; ++r) {
                float d = fmaf(-2.f, acc[pt][ct][r], nv);
                if (d < best[pt][r]) { best[pt][r] = d; bidx[pt][r] = code; }
            }
        }
#pragma unroll
        for (int i = 0; i < 8; ++i) bcur[i] = bnxt[i];
    }

    // butterfly argmin across the 16 code columns (dist, then idx) = first-min
#pragma unroll
    for (int off = 1; off < 16; off <<= 1) {
#pragma unroll
        for (int pt = 0; pt < 4; ++pt)
#pragma unroll
        for (int r = 0; r < 4; ++r) {
            float ob = __shfl_xor(best[pt][r], off, 64);
            int   oi = __shfl_xor(bidx[pt][r], off, 64);
            bool take = (ob < best[pt][r]) || (ob == best[pt][r] && oi < bidx[pt][r]);
            if (take) { best[pt][r] = ob; bidx[pt][r] = oi; }
        }
    }
    if (half == 1 && (l & 15) == 0) {
#pragma unroll
        for (int pt = 0; pt < 4; ++pt)
#pragma unroll
        for (int r = 0; r < 4; ++r) {
            int pix = wp * 64 + pt * 16 + q * 4 + r;
            cbest[pix] = best[pt][r]; cidx[pix] = bidx[pt][r];
        }
    }
    __syncthreads();

    if (half == 0 && (l & 15) == 0) {
        float lp = 0.f;
#pragma unroll
        for (int pt = 0; pt < 4; ++pt)
#pragma unroll
        for (int r = 0; r < 4; ++r) {
            int pix = wp * 64 + pt * 16 + q * 4 + r;
            float fb = best[pt][r]; int fi = bidx[pt][r];
            if (cbest[pix] < fb) { fb = cbest[pix]; fi = cidx[pix]; }  // strict <
            idx_lds[pix] = fi;
            atomicAdd(&cnt_lds[fi], 1u);
            lp += x2_lds[pix] + fb;              // |x-e|^2 = x^2 + (|e|^2 - 2x.e)
        }
        atomicAdd(&red_tot, lp);
    }
    __syncthreads();

    if (t == 0) atomicAdd(ws, red_tot);
    unsigned* gcnt = reinterpret_cast<unsigned*>(ws) + WS_CNT_OFF;
    atomicAdd(gcnt + t, cnt_lds[t]);

    // last-block-done finalize (replaces vq_fin dispatch)
    __threadfence();
    if (t == 0) {
        unsigned old = atomicAdd(gcnt + 512, 1u);
        last_flag = (old == 511u) ? 1u : 0u;
    }
    __syncthreads();
    if (last_flag) {                             // block-uniform branch
        __threadfence();
        unsigned c = atomicAdd(gcnt + t, 0u);    // atomic read-back
        double p = (double)c / (double)NPIX;
        double s = p * log(p + 1e-10);
#pragma unroll
        for (int o = 32; o > 0; o >>= 1) s += __shfl_xor(s, o, 64);
        __shared__ double rd[8];
        if (l == 0) rd[w] = s;
        __syncthreads();
        if (t == 0) {
            double tot = 0.0;
#pragma unroll
            for (int i = 0; i < 8; ++i) tot += rd[i];
            out[OUT_PERP_IDX] = (float)exp(-tot);
            float lv = atomicAdd(ws, 0.f);       // read loss accumulator
            out[0] = 0.25f * lv / (float)NELEM;
        }
    }

    // Epilogue (proven in R3/R4): padded LDS tile -> both layouts coalesced.
    float* out2 = out + OUT_NCHW_OFF;
    float* out3 = out + OUT_NHWC_OFF;
    const float2* emb2 = reinterpret_cast<const float2*>(emb);
    float2* out3_2 = reinterpret_cast<float2*>(out3);

    for (int s = 0; s < 4; ++s) {
#pragma unroll
        for (int it = 0; it < 4; ++it) {         // 2048 float2 / 512 threads
            int fid = it * 512 + t;
            int pp  = fid >> 5;
            int c2  = fid & 31;
            int row = idx_lds[s * 64 + pp];
            float2 v = emb2[row * 32 + c2];
            out3_2[(size_t)(pix0 + s * 64 + pp) * 32 + c2] = v;
            q_lds[pp * 65 + c2 * 2 + 0] = v.x;
            q_lds[pp * 65 + c2 * 2 + 1] = v.y;
        }
        __syncthreads();
#pragma unroll
        for (int it = 0; it < 8; ++it) {         // 4096 floats / 512 threads
            int did = it * 512 + t;
            int c   = did >> 6;
            int hwl = did & 63;
            out2[(size_t)(b * DDIM + c) * HWSZ + hwb + s * 64 + hwl] = q_lds[hwl * 65 + c];
        }
        __syncthreads();
    }
}

extern "C" void kernel_launch(void* const* d_in, const int* in_sizes, int n_in,
                              void* d_out, int out_size, void* d_ws, size_t ws_size,
                              hipStream_t stream) {
    const float* in  = (const float*)d_in[0];
    const float* emb = (const float*)d_in[1];
    float* out = (float*)d_out;
    float* ws  = (float*)d_ws;

    vq_prep<<<32, 256, 0, stream>>>(emb, ws);
    vq_main<<<NPIX / 256, 512, 0, stream>>>(in, emb, out, ws);
}

// Round 6
// 163.983 us; speedup vs baseline: 2.2878x; 2.2878x over previous
//
#include <hip/hip_runtime.h>
#include <math.h>

// Problem constants
#define NPIX   131072      // 32 * 64 * 64 pixels
#define KCODES 512
#define DDIM   64
#define HWSZ   4096        // 64*64
#define NELEM  8388608     // NPIX * DDIM

// d_out layout (fp32): [0]=loss, [1..1+NELEM)=q_nchw, [1+NELEM]=perplexity,
// [2+NELEM .. 2+2*NELEM)=q_nhwc flat
#define OUT_NCHW_OFF 1
#define OUT_PERP_IDX (1 + NELEM)
#define OUT_NHWC_OFF (2 + NELEM)

// ws layout (fp32 words): [0]=loss, [16..528)=|e|^2, [544..1056)=counts(uint),
// [1056]=done counter, [2048..)=e bf16 hi/lo B-fragments (128KB)
#define WS_NRM_OFF  16
#define WS_CNT_OFF  544
#define WS_FRAG_F32 2048

typedef __bf16 bf16x8 __attribute__((ext_vector_type(8)));
typedef float  f32x4  __attribute__((ext_vector_type(4)));

// Prep (verified correct in R5): B-fragment pack + |e|^2 (bit-identical fmaf
// chain to R1/R3/R4) + zero loss/counts/done. ws is re-poisoned every call.
__global__ __launch_bounds__(256) void vq_prep(const float* __restrict__ emb,
                                               float* __restrict__ ws) {
    int tid  = blockIdx.x * 256 + threadIdx.x;   // 0..8191
    int lane = tid & 63;
    int h    = (tid >> 6) & 1;
    int ks   = (tid >> 7) & 1;
    int ct   = tid >> 8;                         // == blockIdx.x (0..31)
    int code = ct * 16 + (lane & 15);
    int d0   = ks * 32 + ((lane >> 4) & 3) * 8;
    const float* src = emb + code * DDIM + d0;
    unsigned short us[8];
#pragma unroll
    for (int j = 0; j < 8; ++j) {
        float f = src[j];
        __bf16 hb = (__bf16)f;                   // RTN
        if (h == 0) {
            us[j] = __builtin_bit_cast(unsigned short, hb);
        } else {
            __bf16 lb = (__bf16)(f - (float)hb);
            us[j] = __builtin_bit_cast(unsigned short, lb);
        }
    }
    uint4 v;
    v.x = us[0] | ((unsigned)us[1] << 16);
    v.y = us[2] | ((unsigned)us[3] << 16);
    v.z = us[4] | ((unsigned)us[5] << 16);
    v.w = us[6] | ((unsigned)us[7] << 16);
    reinterpret_cast<uint4*>(ws + WS_FRAG_F32)[tid] = v;

    if (threadIdx.x < 16) {
        int c = ct * 16 + threadIdx.x;
        const float4* e4 = reinterpret_cast<const float4*>(emb + c * DDIM);
        float s = 0.f;
#pragma unroll
        for (int i = 0; i < 16; ++i) {
            float4 w = e4[i];
            s = fmaf(w.x, w.x, s); s = fmaf(w.y, w.y, s);
            s = fmaf(w.z, w.z, s); s = fmaf(w.w, w.w, s);
        }
        ws[WS_NRM_OFF + c] = s;
    }
    if (blockIdx.x == 0) {
        unsigned* g = reinterpret_cast<unsigned*>(ws);
        g[WS_CNT_OFF + threadIdx.x] = 0u;
        g[WS_CNT_OFF + threadIdx.x + 256] = 0u;
        if (threadIdx.x == 0) { ws[0] = 0.f; g[WS_CNT_OFF + 512] = 0u; }
    }
}

// R4's proven main body (256 thr, launch_bounds(256,2): VGPR=100, NO spill —
// R5's 512-thr/(512,4) variant spilled: VGPR=64, WRITE_SIZE 68->542MB, 5.6x
// slower) + R5's verified last-block-done finalize replacing the vq_fin launch.
__global__ __launch_bounds__(256, 2) void vq_main(const float* __restrict__ in,
                                                  const float* __restrict__ emb,
                                                  float* __restrict__ out,
                                                  float* __restrict__ ws) {
    __shared__ __align__(16) float xs[256 * 68];  // x [pix][d] pad-68; reused as q tile
    __shared__ float    x2_lds[256];
    __shared__ float    nrm_lds[KCODES];
    __shared__ int      idx_lds[256];
    __shared__ unsigned cnt_lds[KCODES];
    __shared__ float    red_tot;
    __shared__ unsigned last_flag;
    __shared__ double   rd[4];

    const int t = threadIdx.x;
    cnt_lds[t] = 0u; cnt_lds[t + 256] = 0u;
    if (t == 0) { red_tot = 0.f; last_flag = 0u; }

    const int pix0 = blockIdx.x << 8;
    const int b    = pix0 >> 12;
    const int hwb  = pix0 & (HWSZ - 1);

    // Stage x (thread t = pixel t): coalesced global reads, b128 LDS writes.
    const float* inb = in + b * (DDIM * HWSZ) + hwb + t;
    float x2 = 0.f;
#pragma unroll
    for (int c = 0; c < DDIM; c += 4) {
        float4 v;
        v.x = inb[(c + 0) * HWSZ]; v.y = inb[(c + 1) * HWSZ];
        v.z = inb[(c + 2) * HWSZ]; v.w = inb[(c + 3) * HWSZ];
        *reinterpret_cast<float4*>(&xs[t * 68 + c]) = v;
        x2 = fmaf(v.x, v.x, x2); x2 = fmaf(v.y, v.y, x2);
        x2 = fmaf(v.z, v.z, x2); x2 = fmaf(v.w, v.w, x2);
    }
    x2_lds[t] = x2;
    nrm_lds[t]       = ws[WS_NRM_OFF + t];
    nrm_lds[t + 256] = ws[WS_NRM_OFF + t + 256];
    __syncthreads();

    const int l = t & 63, wid = t >> 6;   // wave handles pixels [wid*64, +64)

    // A-fragments (A[m][k]: m=lane&15, k=(lane>>4)*8+j), hi/lo bf16 split.
    bf16x8 a_hi[4][2], a_lo[4][2];
#pragma unroll
    for (int pt = 0; pt < 4; ++pt)
#pragma unroll
    for (int ks = 0; ks < 2; ++ks) {
        int pixl = wid * 64 + pt * 16 + (l & 15);
        int d0   = ks * 32 + ((l >> 4) & 3) * 8;
        const float4* p = reinterpret_cast<const float4*>(&xs[pixl * 68 + d0]);
        float4 f0 = p[0], f1 = p[1];
        float fv[8] = {f0.x, f0.y, f0.z, f0.w, f1.x, f1.y, f1.z, f1.w};
        bf16x8 h8, l8;
#pragma unroll
        for (int j = 0; j < 8; ++j) {
            __bf16 hb = (__bf16)fv[j];
            h8[j] = hb;
            l8[j] = (__bf16)(fv[j] - (float)hb);
        }
        a_hi[pt][ks] = h8; a_lo[pt][ks] = l8;
    }

    const uint4* fragp = reinterpret_cast<const uint4*>(ws + WS_FRAG_F32);
    float best[4][4]; int bidx[4][4];
#pragma unroll
    for (int pt = 0; pt < 4; ++pt)
#pragma unroll
    for (int r = 0; r < 4; ++r) { best[pt][r] = 3.4e38f; bidx[pt][r] = 0; }

    // B-frag double buffer: 8 frags/chunk = [ct][ks][h]
    uint4 bcur[8], bnxt[8];
#pragma unroll
    for (int i = 0; i < 8; ++i) {
        int ct = i >> 2, ks = (i >> 1) & 1, h = i & 1;
        bcur[i] = fragp[(((ct) * 2 + ks) * 2 + h) * 64 + l];
    }

    for (int cb = 0; cb < KCODES; cb += 32) {
        int ctb = cb >> 4;
        if (cb + 32 < KCODES) {
#pragma unroll
            for (int i = 0; i < 8; ++i) {
                int ct = i >> 2, ks = (i >> 1) & 1, h = i & 1;
                bnxt[i] = fragp[(((ctb + 2 + ct) * 2 + ks) * 2 + h) * 64 + l];
            }
        }
        f32x4 acc[4][2];
#pragma unroll
        for (int pt = 0; pt < 4; ++pt)
#pragma unroll
        for (int ct = 0; ct < 2; ++ct) {
            f32x4 a = {0.f, 0.f, 0.f, 0.f};
#pragma unroll
            for (int ks = 0; ks < 2; ++ks) {
                bf16x8 bh = __builtin_bit_cast(bf16x8, bcur[ct * 4 + ks * 2 + 0]);
                bf16x8 bl = __builtin_bit_cast(bf16x8, bcur[ct * 4 + ks * 2 + 1]);
                a = __builtin_amdgcn_mfma_f32_16x16x32_bf16(a_hi[pt][ks], bh, a, 0, 0, 0);
                a = __builtin_amdgcn_mfma_f32_16x16x32_bf16(a_hi[pt][ks], bl, a, 0, 0, 0);
                a = __builtin_amdgcn_mfma_f32_16x16x32_bf16(a_lo[pt][ks], bh, a, 0, 0, 0);
                a = __builtin_amdgcn_mfma_f32_16x16x32_bf16(a_lo[pt][ks], bl, a, 0, 0, 0);
            }
            acc[pt][ct] = a;
        }
        // argmin update; C/D: col(code)=lane&15, row(pix)=(lane>>4)*4+reg
#pragma unroll
        for (int ct = 0; ct < 2; ++ct) {
            int code = cb + ct * 16 + (l & 15);
            float nv = nrm_lds[code];
#pragma unroll
            for (int pt = 0; pt < 4; ++pt)
#pragma unroll
            for (int r = 0; r < 4; ++r) {
                float d = fmaf(-2.f, acc[pt][ct][r], nv);
                if (d < best[pt][r]) { best[pt][r] = d; bidx[pt][r] = code; }
            }
        }
#pragma unroll
        for (int i = 0; i < 8; ++i) bcur[i] = bnxt[i];
    }

    // Cross-lane argmin across the 16 code columns; (dist, idx) = first-min.
#pragma unroll
    for (int off = 1; off < 16; off <<= 1) {
#pragma unroll
        for (int pt = 0; pt < 4; ++pt)
#pragma unroll
        for (int r = 0; r < 4; ++r) {
            float ob = __shfl_xor(best[pt][r], off, 64);
            int   oi = __shfl_xor(bidx[pt][r], off, 64);
            bool take = (ob < best[pt][r]) || (ob == best[pt][r] && oi < bidx[pt][r]);
            if (take) { best[pt][r] = ob; bidx[pt][r] = oi; }
        }
    }
    if ((l & 15) == 0) {
        int q = l >> 4;
        float lp = 0.f;
#pragma unroll
        for (int pt = 0; pt < 4; ++pt)
#pragma unroll
        for (int r = 0; r < 4; ++r) {
            int pixl = wid * 64 + pt * 16 + q * 4 + r;
            idx_lds[pixl] = bidx[pt][r];
            atomicAdd(&cnt_lds[bidx[pt][r]], 1u);
            lp += x2_lds[pixl] + best[pt][r];   // |x-e|^2 = x^2 + (|e|^2 - 2x.e)
        }
        atomicAdd(&red_tot, lp);
    }
    __syncthreads();

    if (t == 0) atomicAdd(ws, red_tot);
    unsigned* gcnt = reinterpret_cast<unsigned*>(ws) + WS_CNT_OFF;
    atomicAdd(gcnt + t, cnt_lds[t]);
    atomicAdd(gcnt + t + 256, cnt_lds[t + 256]);

    // Last-block-done finalize (verified in R5) — replaces the vq_fin launch.
    __threadfence();
    if (t == 0) {
        unsigned old = atomicAdd(gcnt + 512, 1u);
        last_flag = (old == 511u) ? 1u : 0u;
    }
    __syncthreads();
    if (last_flag) {                             // block-uniform branch
        __threadfence();
        double s = 0.0;
#pragma unroll
        for (int k = t; k < KCODES; k += 256) {
            unsigned c = atomicAdd(gcnt + k, 0u);   // device-scope read
            double p = (double)c / (double)NPIX;
            s += p * log(p + 1e-10);
        }
#pragma unroll
        for (int o = 32; o > 0; o >>= 1) s += __shfl_xor(s, o, 64);
        if ((t & 63) == 0) rd[t >> 6] = s;
        __syncthreads();
        if (t == 0) {
            double tot = rd[0] + rd[1] + rd[2] + rd[3];
            out[OUT_PERP_IDX] = (float)exp(-tot);
            float lv = atomicAdd(ws, 0.f);       // read loss accumulator
            out[0] = 0.25f * lv / (float)NELEM;
        }
    }

    // Epilogue (proven R3/R4): padded LDS tile (aliases xs) -> both layouts
    // coalesced and LDS-conflict-free.
    float* q_lds = xs;                  // [64][65]
    float* out2 = out + OUT_NCHW_OFF;
    float* out3 = out + OUT_NHWC_OFF;
    const float2* emb2 = reinterpret_cast<const float2*>(emb);
    float2* out3_2 = reinterpret_cast<float2*>(out3);

    for (int s = 0; s < 4; ++s) {
#pragma unroll
        for (int it = 0; it < 8; ++it) {
            int fid = it * 256 + t;
            int pp  = fid >> 5;
            int c2  = fid & 31;
            int row = idx_lds[s * 64 + pp];
            float2 v = emb2[row * 32 + c2];
            out3_2[(size_t)(pix0 + s * 64 + pp) * 32 + c2] = v;
            q_lds[pp * 65 + c2 * 2 + 0] = v.x;
            q_lds[pp * 65 + c2 * 2 + 1] = v.y;
        }
        __syncthreads();
#pragma unroll
        for (int it = 0; it < 16; ++it) {
            int did = it * 256 + t;
            int c   = did >> 6;
            int hwl = did & 63;
            out2[(size_t)(b * DDIM + c) * HWSZ + hwb + s * 64 + hwl] = q_lds[hwl * 65 + c];
        }
        __syncthreads();
    }
}

extern "C" void kernel_launch(void* const* d_in, const int* in_sizes, int n_in,
                              void* d_out, int out_size, void* d_ws, size_t ws_size,
                              hipStream_t stream) {
    const float* in  = (const float*)d_in[0];
    const float* emb = (const float*)d_in[1];
    float* out = (float*)d_out;
    float* ws  = (float*)d_ws;

    vq_prep<<<32, 256, 0, stream>>>(emb, ws);
    vq_main<<<NPIX / 256, 256, 0, stream>>>(in, emb, out, ws);
}